// Round 3
// baseline (145.475 us; speedup 1.0000x reference)
//
#include <hip/hip_runtime.h>

// Attention, 20 slices of [N=1024, D=256]. R8 = R7 + occupancy/schedule:
//  - launch_bounds(256,3): LDS 41KB x3 = 126KB fits, VGPR demand ~140 < 170
//    cap -> 3 blocks/CU, 12 waves/CU, ALL 640 blocks resident (no tail round;
//    R7 ran 512 + a half-empty second round at 2 blocks/CU).
//  - K-DMA(kt+1) issued right after the S-MFMA loop (own af ds_reads provably
//    retired once MFMAs consumed them) -> ~50 more cycles of DMA flight before
//    the vmcnt(8) wait at next iteration top. Queue discipline unchanged:
//    [KDMA(kt+1) x8 older, vf(kt+1) x8 newer], counted waits never drain to 0.
//  - s_setprio(1) around both MFMA clusters (T5: phase-diverse waves regime).

typedef __attribute__((ext_vector_type(8))) short bf16x8;
typedef __attribute__((ext_vector_type(4))) float f32x4;
typedef __attribute__((ext_vector_type(16))) float f32x16;

#define GLD16(gp, lp) __builtin_amdgcn_global_load_lds( \
    (const __attribute__((address_space(1))) unsigned int*)(const void*)(gp), \
    (__attribute__((address_space(3))) unsigned int*)(void*)(lp), 16, 0, 0)

// LDS-only barrier: no vmcnt drain (K-DMA + vf global loads stay in flight)
#define LDS_BARRIER() __asm__ volatile("s_waitcnt lgkmcnt(0)\ns_barrier" ::: "memory")
#define MEMFENCE()    __asm__ volatile("" ::: "memory")
// wait for the 8 oldest VMEM ops (this wave's K-DMA); 8 newer vf loads keep flying
#define WAIT_KDMA()   do { __asm__ volatile("s_waitcnt vmcnt(8)" ::: "memory"); \
                           __builtin_amdgcn_sched_barrier(0); } while (0)

__device__ __forceinline__ unsigned int pack_bf16_rne(float a, float b) {
    unsigned int ua = __float_as_uint(a); ua += 0x7FFFu + ((ua >> 16) & 1u);
    unsigned int ub = __float_as_uint(b); ub += 0x7FFFu + ((ub >> 16) & 1u);
    return (ua >> 16) | (ub & 0xFFFF0000u);
}
__device__ __forceinline__ unsigned int pack2_trunc(float lo, float hi) {
    return __builtin_amdgcn_perm(__float_as_uint(hi), __float_as_uint(lo), 0x07060302u);
}

// Fused prep: bid<640 -> XV tiles, else -> XT tiles. x is [slice][d=256][n=1024].
// XT[slice][n][chunk^(n&7)] bf16 (16B-chunk XOR swizzle, for conflict-free Kmd
// ds_reads).  XV[slice][cc=m>>3][d][j=m&7] bf16 (16B cells, V B-frags contig).
__global__ __launch_bounds__(256) void prep_kernel(const float* __restrict__ x,
                                                   unsigned short* __restrict__ XT,
                                                   unsigned short* __restrict__ XV) {
    __shared__ __align__(16) unsigned char smem[16384];
    int bid = blockIdx.x;
    int t = threadIdx.x;
    if (bid < 640) {
        // XV: transpose a 32cc x 32d tile of 16B cells through LDS.
        uint4* T = (uint4*)smem;                      // [32cc][32d'] 16KB
        int slice = bid >> 5, w = bid & 31;
        int cc0 = (w & 3) * 32, d0 = (w >> 2) * 32;
        const float* xs = x + slice * 262144;
        int ccl = t & 31, dr = t >> 5;                // load: lanes->cc (1KB coalesced)
        #pragma unroll
        for (int p = 0; p < 4; ++p) {
            int dl = p * 8 + dr;
            const float* src = xs + (d0 + dl) * 1024 + (cc0 + ccl) * 8;
            float4 a = *(const float4*)(src);
            float4 b = *(const float4*)(src + 4);
            uint4 o;
            o.x = pack_bf16_rne(a.x, a.y); o.y = pack_bf16_rne(a.z, a.w);
            o.z = pack_bf16_rne(b.x, b.y); o.w = pack_bf16_rne(b.z, b.w);
            T[ccl * 32 + (dl ^ ccl)] = o;             // XOR-swizzled cell
        }
        __syncthreads();
        unsigned short* xv = XV + slice * 262144;
        int dl2 = t & 31, cr = t >> 5;                // store: lanes->d (512B segments)
        #pragma unroll
        for (int p = 0; p < 4; ++p) {
            int ccl2 = p * 8 + cr;
            uint4 o = T[ccl2 * 32 + (dl2 ^ ccl2)];
            *(uint4*)(xv + ((cc0 + ccl2) * 256 + d0 + dl2) * 8) = o;
        }
    } else {
        // XT: 128d x 64n tile, 4x4 micro-tile transpose via LDS.
        unsigned long long* TX = (unsigned long long*)smem;   // [64n][32dq] 8B, 16KB
        int b = bid - 640;
        int slice = b >> 5, w = b & 31;
        int d0 = (w & 1) * 128, n0 = (w >> 1) * 64;
        const float* xs = x + slice * 262144;
        int nq = t & 15, dqh = t >> 4;
        #pragma unroll
        for (int p = 0; p < 2; ++p) {
            int dq = p * 16 + dqh;                    // d = d0 + dq*4
            const float* src = xs + (d0 + dq * 4) * 1024 + n0 + nq * 4;
            float4 r0 = *(const float4*)(src);
            float4 r1 = *(const float4*)(src + 1024);
            float4 r2 = *(const float4*)(src + 2048);
            float4 r3 = *(const float4*)(src + 3072);
            const float* f0 = (const float*)&r0; const float* f1 = (const float*)&r1;
            const float* f2 = (const float*)&r2; const float* f3 = (const float*)&r3;
            #pragma unroll
            for (int j = 0; j < 4; ++j) {
                int nl2 = nq * 4 + j;
                unsigned long long q = (unsigned long long)pack_bf16_rne(f0[j], f1[j])
                    | ((unsigned long long)pack_bf16_rne(f2[j], f3[j]) << 32);
                TX[nl2 * 32 + (dq ^ (nl2 & 31))] = q;
            }
        }
        __syncthreads();
        unsigned short* xt = XT + slice * 262144;
        int ch = t & 15, nr = t >> 4;
        #pragma unroll
        for (int p = 0; p < 4; ++p) {
            int nl2 = p * 16 + nr;
            unsigned long long qlo = TX[nl2 * 32 + ((ch * 2) ^ (nl2 & 31))];
            unsigned long long qhi = TX[nl2 * 32 + ((ch * 2 + 1) ^ (nl2 & 31))];
            uint4 o = make_uint4((unsigned int)qlo, (unsigned int)(qlo >> 32),
                                 (unsigned int)qhi, (unsigned int)(qhi >> 32));
            // chunk index = (d0>>3)+ch, stored at chunk^(n&7) (Kmd read swizzle)
            *(uint4*)(xt + (n0 + nl2) * 256 + ((((d0 >> 3) + ch) ^ (nl2 & 7)) * 8)) = o;
        }
    }
}

__global__ __launch_bounds__(256, 3) void attn_kernel(const unsigned short* __restrict__ XT,
                                                      const unsigned short* __restrict__ XV,
                                                      const int* __restrict__ beta,
                                                      float* __restrict__ out) {
    __shared__ __align__(16) unsigned short Kmd[64 * 256];    // 32KB K-tile [m][chunk^swz]
    __shared__ __align__(16) unsigned short Pb[2][32 * 64];   // P dbuf, 8KB
    __shared__ float Lpart[4 * 32];
    __shared__ __align__(16) float Ltot[32];

    int bid = blockIdx.x;
    int t = ((bid & 7) * 80) + (bid >> 3);      // XCD-locality swizzle (640 blocks)
    int slice = t >> 5, qh = t & 31;

    int tid = threadIdx.x;
    int lane = tid & 63, wv = tid >> 6;
    int nl = lane & 15, g = lane >> 4;          // 16x16 frame
    int lo = lane & 31, hi = lane >> 5;         // 32x32 frame

    const unsigned short* xt_s = XT + slice * 262144;
    const unsigned short* xv_s = XV + slice * 262144;
    float cscale = (float)(beta[0]) * 1.44269504089f;   // beta * log2(e)

    // ---- prologue: issue K-DMA(0) FIRST (oldest in vm queue) ----
    #pragma unroll
    for (int i = 0; i < 8; ++i) {
        int ch = wv * 8 + i;
        GLD16(xt_s + ch * 512 + lane * 8, &Kmd[ch * 512]);
    }
    MEMFENCE();   // keep qf/vf loads AFTER the DMA issues in the vm queue

    // ---- Q fragments (2 strips of 16 n) + fixed softmax max per column ----
    bf16x8 qf[2][8];
    float mcol[2];
    #pragma unroll
    for (int nq = 0; nq < 2; ++nq) {
        int n = qh * 32 + nq * 16 + nl;
        const unsigned short* qrow = xt_s + n * 256;
        float dg = 0.f;
        #pragma unroll
        for (int ks = 0; ks < 8; ++ks) {
            qf[nq][ks] = *(const bf16x8*)(qrow + (((ks * 4 + g) ^ (n & 7)) * 8));
            const unsigned int* qu = (const unsigned int*)&qf[nq][ks];
            #pragma unroll
            for (int w = 0; w < 4; ++w) {
                float flo = __uint_as_float(qu[w] << 16);
                float fhi = __uint_as_float(qu[w] & 0xFFFF0000u);
                dg = fmaf(flo, flo, dg);
                dg = fmaf(fhi, fhi, dg);
            }
        }
        dg += __shfl_xor(dg, 16);
        dg += __shfl_xor(dg, 32);
        mcol[nq] = dg * cscale;   // consumes all qf loads -> they retire here
    }

    f32x16 acc[2];                   // O[32n x 64d]: wave owns d in [wv*64,+64)
    acc[0] = (f32x16)(0.f); acc[1] = (f32x16)(0.f);
    float lac0 = 0.f, lac1 = 0.f;

    // vf(kt,ks,db) = XV cell (cc = kt*8 + ks*2 + hi, d = wv*64 + db*32 + lo)
    const unsigned short* vb = xv_s + (hi * 256 + wv * 64 + lo) * 8;
    bf16x8 vf[8];
    MEMFENCE();   // vf(0) loads stay after K-DMA(0) in issue order
    #pragma unroll
    for (int ks = 0; ks < 4; ++ks) {
        vf[ks * 2]     = *(const bf16x8*)(vb + ks * 4096);
        vf[ks * 2 + 1] = *(const bf16x8*)(vb + ks * 4096 + 256);
    }
    // vm queue now: [K-DMA(0) x8 oldest][vf(0) x8 newest] = 16 outstanding

    const unsigned short* kmd_row = &Kmd[(wv * 16 + nl) * 256];

    for (int kt = 0; kt < 16; ++kt) {
        WAIT_KDMA();                 // vmcnt(8): Kmd(kt) landed; vf(kt) still flying

        // ---- S(kt): wave's own 16m rows x both 16n strips (A-frag reused) ----
        f32x4 s0 = {0.f,0.f,0.f,0.f}, s1 = {0.f,0.f,0.f,0.f};
        __builtin_amdgcn_s_setprio(1);
        #pragma unroll
        for (int ks = 0; ks < 8; ++ks) {
            bf16x8 af = *(const bf16x8*)(kmd_row + (((ks * 4 + g) ^ (nl & 7)) * 8));
            s0 = __builtin_amdgcn_mfma_f32_16x16x32_bf16(af, qf[0][ks], s0, 0, 0, 0);
            s1 = __builtin_amdgcn_mfma_f32_16x16x32_bf16(af, qf[1][ks], s1, 0, 0, 0);
        }
        __builtin_amdgcn_s_setprio(0);
        __builtin_amdgcn_sched_barrier(0);   // af ds_reads retired (consumed above):
                                             // safe to overwrite own Kmd rows now
        // restage own Kmd rows for kt+1 (DMA flies across softmax+barrier+PV)
        if (kt < 15) {
            const unsigned short* gk = xt_s + (kt + 1) * 16384;
            #pragma unroll
            for (int i = 0; i < 8; ++i) {
                int ch = wv * 8 + i;
                GLD16(gk + ch * 512 + lane * 8, &Kmd[ch * 512]);
            }
        }
        MEMFENCE();

        // ---- softmax (fixed max) + P write -> Pb[kt&1] ----
        {
            float p0 = exp2f(fmaf(s0[0], cscale, -mcol[0]));
            float p1 = exp2f(fmaf(s0[1], cscale, -mcol[0]));
            float p2 = exp2f(fmaf(s0[2], cscale, -mcol[0]));
            float p3 = exp2f(fmaf(s0[3], cscale, -mcol[0]));
            lac0 += (p0 + p1) + (p2 + p3);
            *(uint2*)(&Pb[kt & 1][nl * 64 + (((wv * 2 + (g >> 1)) ^ (nl & 7)) * 8) + (g & 1) * 4]) =
                make_uint2(pack2_trunc(p0, p1), pack2_trunc(p2, p3));
        }
        {
            float p0 = exp2f(fmaf(s1[0], cscale, -mcol[1]));
            float p1 = exp2f(fmaf(s1[1], cscale, -mcol[1]));
            float p2 = exp2f(fmaf(s1[2], cscale, -mcol[1]));
            float p3 = exp2f(fmaf(s1[3], cscale, -mcol[1]));
            lac1 += (p0 + p1) + (p2 + p3);
            *(uint2*)(&Pb[kt & 1][(16 + nl) * 64 + (((wv * 2 + (g >> 1)) ^ (nl & 7)) * 8) + (g & 1) * 4]) =
                make_uint2(pack2_trunc(p0, p1), pack2_trunc(p2, p3));
        }

        LDS_BARRIER();               // the ONLY barrier per kt: P(kt) visible to all

        // ---- PV(kt): O += P[32n x 64m] * V[64m x 64d], vf in regs; reload vf(kt+1)
        {
            const unsigned short* vnext = vb + (kt + 1) * 16384;
            __builtin_amdgcn_s_setprio(1);
            #pragma unroll
            for (int ks = 0; ks < 4; ++ks) {
                bf16x8 pf = *(const bf16x8*)(&Pb[kt & 1][lo * 64 + (((ks * 2 + hi) ^ (lo & 7)) * 8)]);
                acc[0] = __builtin_amdgcn_mfma_f32_32x32x16_bf16(pf, vf[ks * 2],     acc[0], 0, 0, 0);
                acc[1] = __builtin_amdgcn_mfma_f32_32x32x16_bf16(pf, vf[ks * 2 + 1], acc[1], 0, 0, 0);
                if (kt < 15) {
                    vf[ks * 2]     = *(const bf16x8*)(vnext + ks * 4096);
                    vf[ks * 2 + 1] = *(const bf16x8*)(vnext + ks * 4096 + 256);
                }
            }
            __builtin_amdgcn_s_setprio(0);
        }
        // vm queue at loop top: [K-DMA(kt+1) x8 oldest][vf(kt+1) x8] = 16
    }

    // ---- epilogue: softmax denominators, scale, store ----
    lac0 += __shfl_xor(lac0, 16); lac0 += __shfl_xor(lac0, 32);
    lac1 += __shfl_xor(lac1, 16); lac1 += __shfl_xor(lac1, 32);
    if (lane < 16) {
        Lpart[wv * 32 + nl] = lac0;
        Lpart[wv * 32 + 16 + nl] = lac1;
    }
    LDS_BARRIER();
    if (tid < 32)
        Ltot[tid] = 1.f / (Lpart[tid] + Lpart[32 + tid] + Lpart[64 + tid] + Lpart[96 + tid]);
    LDS_BARRIER();

    float* outs = out + slice * 262144 + (qh * 32) * 256;
    #pragma unroll
    for (int rq = 0; rq < 4; ++rq) {
        f32x4 li = *(const f32x4*)(&Ltot[rq * 8 + hi * 4]);
        #pragma unroll
        for (int j = 0; j < 4; ++j) {
            int nloc = rq * 8 + hi * 4 + j;
            #pragma unroll
            for (int db = 0; db < 2; ++db)
                outs[nloc * 256 + wv * 64 + db * 32 + lo] = acc[db][rq * 4 + j] * li[j];
        }
    }
}

extern "C" void kernel_launch(void* const* d_in, const int* in_sizes, int n_in,
                              void* d_out, int out_size, void* d_ws, size_t ws_size,
                              hipStream_t stream) {
    const float* x = (const float*)d_in[0];
    const int* beta = (const int*)d_in[1];
    float* out = (float*)d_out;
    unsigned short* XT = (unsigned short*)d_ws;                 // 10,485,760 B
    unsigned short* XV = (unsigned short*)d_ws + 5242880;       // 10,485,760 B
    prep_kernel<<<1280, 256, 0, stream>>>(x, XT, XV);
    attn_kernel<<<640, 256, 0, stream>>>(XT, XV, beta, out);
}

// Round 4
// 121.821 us; speedup vs baseline: 1.1942x; 1.1942x over previous
//
#include <hip/hip_runtime.h>

// Attention, 20 slices of [N=1024, D=256]. R9 = R7 envelope (launch_bounds
// (256,2): no spill) + latency-chain fixes:
//  - PV lag-1: loop is S(kt) -> KDMA(kt+1) -> softmax(kt) -> PV(kt-1) ->
//    barrier. Barrier-wait (inter-wave softmax skew) now overlapped by PV
//    MFMAs instead of being dead time. Pb stays double-buffered; one
//    lgkmcnt-only barrier per kt bounds skew to <1 iter (WAR on Pb safe).
//  - vm-queue: iter kt issues [KDMA(kt+1) x8, vf(kt) x8] in order -> top
//    vmcnt(8) waits own K only; PV's vf consumption gets compiler-counted
//    vmcnt (vf oldest at that point) -> nothing ever drains to 0 in-loop.
//    Peeled iter 0 uses vmcnt(0) once (KDMA(0) flight = Q-norm prologue).
//  - S split into 4 independent MFMA chains (4-deep, was 2x8-deep), folded
//    with 8 v_add: halves the S dependent-latency chain, +8 transient regs.
//  - R8's (256,3) regression root-caused: compiler accum-offset split under
//    the 168-reg cap wasted ~50 regs -> 18.5MB spill (WRITE 39MB). Reverted.

typedef __attribute__((ext_vector_type(8))) short bf16x8;
typedef __attribute__((ext_vector_type(4))) float f32x4;
typedef __attribute__((ext_vector_type(16))) float f32x16;

#define GLD16(gp, lp) __builtin_amdgcn_global_load_lds( \
    (const __attribute__((address_space(1))) unsigned int*)(const void*)(gp), \
    (__attribute__((address_space(3))) unsigned int*)(void*)(lp), 16, 0, 0)

// LDS-only barrier: no vmcnt drain (K-DMA + vf global loads stay in flight)
#define LDS_BARRIER() __asm__ volatile("s_waitcnt lgkmcnt(0)\ns_barrier" ::: "memory")
#define MEMFENCE()    __asm__ volatile("" ::: "memory")
// wait the 8 oldest VMEM ops (this wave's K-DMA); 8 newer vf loads keep flying
#define WAIT_KDMA()   do { __asm__ volatile("s_waitcnt vmcnt(8)" ::: "memory"); \
                           __builtin_amdgcn_sched_barrier(0); } while (0)
#define WAIT_ALL_VM() do { __asm__ volatile("s_waitcnt vmcnt(0)" ::: "memory"); \
                           __builtin_amdgcn_sched_barrier(0); } while (0)

__device__ __forceinline__ unsigned int pack_bf16_rne(float a, float b) {
    unsigned int ua = __float_as_uint(a); ua += 0x7FFFu + ((ua >> 16) & 1u);
    unsigned int ub = __float_as_uint(b); ub += 0x7FFFu + ((ub >> 16) & 1u);
    return (ua >> 16) | (ub & 0xFFFF0000u);
}
__device__ __forceinline__ unsigned int pack2_trunc(float lo, float hi) {
    return __builtin_amdgcn_perm(__float_as_uint(hi), __float_as_uint(lo), 0x07060302u);
}

// Fused prep: bid<640 -> XV tiles, else -> XT tiles. x is [slice][d=256][n=1024].
// XT[slice][n][chunk^(n&7)] bf16 (16B-chunk XOR swizzle, conflict-free Kmd
// ds_reads).  XV[slice][cc=m>>3][d][j=m&7] bf16 (16B cells, V B-frags contig).
__global__ __launch_bounds__(256) void prep_kernel(const float* __restrict__ x,
                                                   unsigned short* __restrict__ XT,
                                                   unsigned short* __restrict__ XV) {
    __shared__ __align__(16) unsigned char smem[16384];
    int bid = blockIdx.x;
    int t = threadIdx.x;
    if (bid < 640) {
        uint4* T = (uint4*)smem;                      // [32cc][32d'] 16KB
        int slice = bid >> 5, w = bid & 31;
        int cc0 = (w & 3) * 32, d0 = (w >> 2) * 32;
        const float* xs = x + slice * 262144;
        int ccl = t & 31, dr = t >> 5;                // load: lanes->cc (1KB coalesced)
        #pragma unroll
        for (int p = 0; p < 4; ++p) {
            int dl = p * 8 + dr;
            const float* src = xs + (d0 + dl) * 1024 + (cc0 + ccl) * 8;
            float4 a = *(const float4*)(src);
            float4 b = *(const float4*)(src + 4);
            uint4 o;
            o.x = pack_bf16_rne(a.x, a.y); o.y = pack_bf16_rne(a.z, a.w);
            o.z = pack_bf16_rne(b.x, b.y); o.w = pack_bf16_rne(b.z, b.w);
            T[ccl * 32 + (dl ^ ccl)] = o;             // XOR-swizzled cell
        }
        __syncthreads();
        unsigned short* xv = XV + slice * 262144;
        int dl2 = t & 31, cr = t >> 5;                // store: lanes->d (512B segments)
        #pragma unroll
        for (int p = 0; p < 4; ++p) {
            int ccl2 = p * 8 + cr;
            uint4 o = T[ccl2 * 32 + (dl2 ^ ccl2)];
            *(uint4*)(xv + ((cc0 + ccl2) * 256 + d0 + dl2) * 8) = o;
        }
    } else {
        unsigned long long* TX = (unsigned long long*)smem;   // [64n][32dq] 8B, 16KB
        int b = bid - 640;
        int slice = b >> 5, w = b & 31;
        int d0 = (w & 1) * 128, n0 = (w >> 1) * 64;
        const float* xs = x + slice * 262144;
        int nq = t & 15, dqh = t >> 4;
        #pragma unroll
        for (int p = 0; p < 2; ++p) {
            int dq = p * 16 + dqh;                    // d = d0 + dq*4
            const float* src = xs + (d0 + dq * 4) * 1024 + n0 + nq * 4;
            float4 r0 = *(const float4*)(src);
            float4 r1 = *(const float4*)(src + 1024);
            float4 r2 = *(const float4*)(src + 2048);
            float4 r3 = *(const float4*)(src + 3072);
            const float* f0 = (const float*)&r0; const float* f1 = (const float*)&r1;
            const float* f2 = (const float*)&r2; const float* f3 = (const float*)&r3;
            #pragma unroll
            for (int j = 0; j < 4; ++j) {
                int nl2 = nq * 4 + j;
                unsigned long long q = (unsigned long long)pack_bf16_rne(f0[j], f1[j])
                    | ((unsigned long long)pack_bf16_rne(f2[j], f3[j]) << 32);
                TX[nl2 * 32 + (dq ^ (nl2 & 31))] = q;
            }
        }
        __syncthreads();
        unsigned short* xt = XT + slice * 262144;
        int ch = t & 15, nr = t >> 4;
        #pragma unroll
        for (int p = 0; p < 4; ++p) {
            int nl2 = p * 16 + nr;
            unsigned long long qlo = TX[nl2 * 32 + ((ch * 2) ^ (nl2 & 31))];
            unsigned long long qhi = TX[nl2 * 32 + ((ch * 2 + 1) ^ (nl2 & 31))];
            uint4 o = make_uint4((unsigned int)qlo, (unsigned int)(qlo >> 32),
                                 (unsigned int)qhi, (unsigned int)(qhi >> 32));
            *(uint4*)(xt + (n0 + nl2) * 256 + ((((d0 >> 3) + ch) ^ (nl2 & 7)) * 8)) = o;
        }
    }
}

__global__ __launch_bounds__(256, 2) void attn_kernel(const unsigned short* __restrict__ XT,
                                                      const unsigned short* __restrict__ XV,
                                                      const int* __restrict__ beta,
                                                      float* __restrict__ out) {
    __shared__ __align__(16) unsigned short Kmd[64 * 256];    // 32KB K-tile [m][chunk^swz]
    __shared__ __align__(16) unsigned short Pb[2][32 * 64];   // P dbuf, 8KB
    __shared__ float Lpart[4 * 32];
    __shared__ __align__(16) float Ltot[32];

    int bid = blockIdx.x;
    int t = ((bid & 7) * 80) + (bid >> 3);      // XCD-locality swizzle (640 blocks)
    int slice = t >> 5, qh = t & 31;

    int tid = threadIdx.x;
    int lane = tid & 63, wv = tid >> 6;
    int nl = lane & 15, g = lane >> 4;          // 16x16 frame
    int lo = lane & 31, hi = lane >> 5;         // 32x32 frame

    const unsigned short* xt_s = XT + slice * 262144;
    const unsigned short* xv_s = XV + slice * 262144;
    float cscale = (float)(beta[0]) * 1.44269504089f;   // beta * log2(e)

    // ---- prologue: issue K-DMA(0) FIRST (oldest in vm queue) ----
    #pragma unroll
    for (int i = 0; i < 8; ++i) {
        int ch = wv * 8 + i;
        GLD16(xt_s + ch * 512 + lane * 8, &Kmd[ch * 512]);
    }
    MEMFENCE();

    // ---- Q fragments (2 strips of 16 n) + fixed softmax max per column ----
    bf16x8 qf[2][8];
    float mcol[2];
    #pragma unroll
    for (int nq = 0; nq < 2; ++nq) {
        int n = qh * 32 + nq * 16 + nl;
        const unsigned short* qrow = xt_s + n * 256;
        float dg = 0.f;
        #pragma unroll
        for (int ks = 0; ks < 8; ++ks) {
            qf[nq][ks] = *(const bf16x8*)(qrow + (((ks * 4 + g) ^ (n & 7)) * 8));
            const unsigned int* qu = (const unsigned int*)&qf[nq][ks];
            #pragma unroll
            for (int w = 0; w < 4; ++w) {
                float flo = __uint_as_float(qu[w] << 16);
                float fhi = __uint_as_float(qu[w] & 0xFFFF0000u);
                dg = fmaf(flo, flo, dg);
                dg = fmaf(fhi, fhi, dg);
            }
        }
        dg += __shfl_xor(dg, 16);
        dg += __shfl_xor(dg, 32);
        mcol[nq] = dg * cscale;   // consumes all qf loads -> they retire here
    }

    f32x16 acc[2];                   // O[32n x 64d]: wave owns d in [wv*64,+64)
    acc[0] = (f32x16)(0.f); acc[1] = (f32x16)(0.f);
    float lac0 = 0.f, lac1 = 0.f;

    // vf(kt,ks,db) = XV cell (cc = kt*8 + ks*2 + hi, d = wv*64 + db*32 + lo)
    const unsigned short* vb = xv_s + (hi * 256 + wv * 64 + lo) * 8;
    bf16x8 vf[8];

    const unsigned short* kmd_row = &Kmd[(wv * 16 + nl) * 256];

    // S(kt): 4 independent 4-deep MFMA chains, folded at the end
    auto S_mfma = [&](f32x4& s0, f32x4& s1) {
        f32x4 s0a = {0.f,0.f,0.f,0.f}, s0b = {0.f,0.f,0.f,0.f};
        f32x4 s1a = {0.f,0.f,0.f,0.f}, s1b = {0.f,0.f,0.f,0.f};
        __builtin_amdgcn_s_setprio(1);
        #pragma unroll
        for (int ks = 0; ks < 4; ++ks) {
            bf16x8 af0 = *(const bf16x8*)(kmd_row + ((((2 * ks) * 4 + g) ^ (nl & 7)) * 8));
            bf16x8 af1 = *(const bf16x8*)(kmd_row + ((((2 * ks + 1) * 4 + g) ^ (nl & 7)) * 8));
            s0a = __builtin_amdgcn_mfma_f32_16x16x32_bf16(af0, qf[0][2 * ks], s0a, 0, 0, 0);
            s1a = __builtin_amdgcn_mfma_f32_16x16x32_bf16(af0, qf[1][2 * ks], s1a, 0, 0, 0);
            s0b = __builtin_amdgcn_mfma_f32_16x16x32_bf16(af1, qf[0][2 * ks + 1], s0b, 0, 0, 0);
            s1b = __builtin_amdgcn_mfma_f32_16x16x32_bf16(af1, qf[1][2 * ks + 1], s1b, 0, 0, 0);
        }
        __builtin_amdgcn_s_setprio(0);
        s0 = s0a + s0b; s1 = s1a + s1b;
    };

    auto softmax_store = [&](const f32x4& s0, const f32x4& s1, int pbi) {
        {
            float p0 = exp2f(fmaf(s0[0], cscale, -mcol[0]));
            float p1 = exp2f(fmaf(s0[1], cscale, -mcol[0]));
            float p2 = exp2f(fmaf(s0[2], cscale, -mcol[0]));
            float p3 = exp2f(fmaf(s0[3], cscale, -mcol[0]));
            lac0 += (p0 + p1) + (p2 + p3);
            *(uint2*)(&Pb[pbi][nl * 64 + (((wv * 2 + (g >> 1)) ^ (nl & 7)) * 8) + (g & 1) * 4]) =
                make_uint2(pack2_trunc(p0, p1), pack2_trunc(p2, p3));
        }
        {
            float p0 = exp2f(fmaf(s1[0], cscale, -mcol[1]));
            float p1 = exp2f(fmaf(s1[1], cscale, -mcol[1]));
            float p2 = exp2f(fmaf(s1[2], cscale, -mcol[1]));
            float p3 = exp2f(fmaf(s1[3], cscale, -mcol[1]));
            lac1 += (p0 + p1) + (p2 + p3);
            *(uint2*)(&Pb[pbi][(16 + nl) * 64 + (((wv * 2 + (g >> 1)) ^ (nl & 7)) * 8) + (g & 1) * 4]) =
                make_uint2(pack2_trunc(p0, p1), pack2_trunc(p2, p3));
        }
    };

    auto kdma = [&](int kt) {
        const unsigned short* gk = xt_s + kt * 16384;
        #pragma unroll
        for (int i = 0; i < 8; ++i) {
            int ch = wv * 8 + i;
            GLD16(gk + ch * 512 + lane * 8, &Kmd[ch * 512]);
        }
    };

    // ---- peeled iter 0: S(0), KDMA(1), sm(0), vf(0) loads, barrier ----
    {
        WAIT_ALL_VM();               // one-time: KDMA(0) flight = Q prologue
        f32x4 s0, s1;
        S_mfma(s0, s1);
        __builtin_amdgcn_sched_barrier(0);   // own af reads retired: Kmd rewritable
        kdma(1);
        MEMFENCE();
        softmax_store(s0, s1, 0);
        #pragma unroll
        for (int ks = 0; ks < 4; ++ks) {     // vf(0): issued AFTER KDMA(1)
            vf[ks * 2]     = *(const bf16x8*)(vb + ks * 4096);
            vf[ks * 2 + 1] = *(const bf16x8*)(vb + ks * 4096 + 256);
        }
        LDS_BARRIER();
    }
    // vm queue at loop top: [KDMA(kt) x8 older][vf(kt-1) x8 newer] = 16

    for (int kt = 1; kt < 16; ++kt) {
        WAIT_KDMA();                 // vmcnt(8): Kmd(kt) landed; vf(kt-1) flying

        f32x4 s0, s1;
        S_mfma(s0, s1);
        __builtin_amdgcn_sched_barrier(0);   // own af reads retired
        if (kt < 15) kdma(kt + 1);
        MEMFENCE();
        softmax_store(s0, s1, kt & 1);

        // ---- PV(kt-1): overlaps the former barrier-wait; reload vf -> vf(kt)
        {
            const unsigned short* vkt = vb + kt * 16384;
            __builtin_amdgcn_s_setprio(1);
            #pragma unroll
            for (int ks = 0; ks < 4; ++ks) {
                bf16x8 pf = *(const bf16x8*)(&Pb[(kt - 1) & 1][lo * 64 + (((ks * 2 + hi) ^ (lo & 7)) * 8)]);
                acc[0] = __builtin_amdgcn_mfma_f32_32x32x16_bf16(pf, vf[ks * 2],     acc[0], 0, 0, 0);
                acc[1] = __builtin_amdgcn_mfma_f32_32x32x16_bf16(pf, vf[ks * 2 + 1], acc[1], 0, 0, 0);
                vf[ks * 2]     = *(const bf16x8*)(vkt + ks * 4096);
                vf[ks * 2 + 1] = *(const bf16x8*)(vkt + ks * 4096 + 256);
            }
            __builtin_amdgcn_s_setprio(0);
        }

        LDS_BARRIER();               // the ONLY barrier per kt: P(kt) visible
    }

    // ---- epilogue PV(15): Pb[1] (post-barrier), vf(15) in regs ----
    #pragma unroll
    for (int ks = 0; ks < 4; ++ks) {
        bf16x8 pf = *(const bf16x8*)(&Pb[1][lo * 64 + (((ks * 2 + hi) ^ (lo & 7)) * 8)]);
        acc[0] = __builtin_amdgcn_mfma_f32_32x32x16_bf16(pf, vf[ks * 2],     acc[0], 0, 0, 0);
        acc[1] = __builtin_amdgcn_mfma_f32_32x32x16_bf16(pf, vf[ks * 2 + 1], acc[1], 0, 0, 0);
    }

    // ---- softmax denominators, scale, store ----
    lac0 += __shfl_xor(lac0, 16); lac0 += __shfl_xor(lac0, 32);
    lac1 += __shfl_xor(lac1, 16); lac1 += __shfl_xor(lac1, 32);
    if (lane < 16) {
        Lpart[wv * 32 + nl] = lac0;
        Lpart[wv * 32 + 16 + nl] = lac1;
    }
    LDS_BARRIER();
    if (tid < 32)
        Ltot[tid] = 1.f / (Lpart[tid] + Lpart[32 + tid] + Lpart[64 + tid] + Lpart[96 + tid]);
    LDS_BARRIER();

    float* outs = out + slice * 262144 + (qh * 32) * 256;
    #pragma unroll
    for (int rq = 0; rq < 4; ++rq) {
        f32x4 li = *(const f32x4*)(&Ltot[rq * 8 + hi * 4]);
        #pragma unroll
        for (int j = 0; j < 4; ++j) {
            int nloc = rq * 8 + hi * 4 + j;
            #pragma unroll
            for (int db = 0; db < 2; ++db)
                outs[nloc * 256 + wv * 64 + db * 32 + lo] = acc[db][rq * 4 + j] * li[j];
        }
    }
}

extern "C" void kernel_launch(void* const* d_in, const int* in_sizes, int n_in,
                              void* d_out, int out_size, void* d_ws, size_t ws_size,
                              hipStream_t stream) {
    const float* x = (const float*)d_in[0];
    const int* beta = (const int*)d_in[1];
    float* out = (float*)d_out;
    unsigned short* XT = (unsigned short*)d_ws;                 // 10,485,760 B
    unsigned short* XV = (unsigned short*)d_ws + 5242880;       // 10,485,760 B
    prep_kernel<<<1280, 256, 0, stream>>>(x, XT, XV);
    attn_kernel<<<640, 256, 0, stream>>>(XT, XV, beta, out);
}

// Round 5
// 119.232 us; speedup vs baseline: 1.2201x; 1.0217x over previous
//
#include <hip/hip_runtime.h>

// Attention, 20 slices of [N=1024, D=256]. R10 = R7 (best, 46us) + ONE change:
// double-buffered Kmd (2x32KB LDS). KDMA(kt+2) is issued at iter kt ->
// >=1.4 iterations (~1500cy) of flight before its wait, covering cold-L3
// (~900cy) K-tile latency that R7's single-buffer (~300cy flight) exposed
// every iteration. Counted waits only: top-of-iter vmcnt(16) in steady state
// (KDMA(kt) oldest; KDMA(kt+1) x8 + vf(kt) x8 newer), vmcnt(8) at kt=15.
// Everything else is exactly R7 (R9's bundle of PV-lag-1/S-split/setprio
// regressed 46->52.5; reverted). LDS 74.4KB -> still 2 blocks/CU at (256,2).

typedef __attribute__((ext_vector_type(8))) short bf16x8;
typedef __attribute__((ext_vector_type(4))) float f32x4;
typedef __attribute__((ext_vector_type(16))) float f32x16;

#define GLD16(gp, lp) __builtin_amdgcn_global_load_lds( \
    (const __attribute__((address_space(1))) unsigned int*)(const void*)(gp), \
    (__attribute__((address_space(3))) unsigned int*)(void*)(lp), 16, 0, 0)

// LDS-only barrier: no vmcnt drain (K-DMA + vf global loads stay in flight)
#define LDS_BARRIER() __asm__ volatile("s_waitcnt lgkmcnt(0)\ns_barrier" ::: "memory")
#define MEMFENCE()    __asm__ volatile("" ::: "memory")

__device__ __forceinline__ unsigned int pack_bf16_rne(float a, float b) {
    unsigned int ua = __float_as_uint(a); ua += 0x7FFFu + ((ua >> 16) & 1u);
    unsigned int ub = __float_as_uint(b); ub += 0x7FFFu + ((ub >> 16) & 1u);
    return (ua >> 16) | (ub & 0xFFFF0000u);
}
__device__ __forceinline__ unsigned int pack2_trunc(float lo, float hi) {
    return __builtin_amdgcn_perm(__float_as_uint(hi), __float_as_uint(lo), 0x07060302u);
}

// Fused prep: bid<640 -> XV tiles, else -> XT tiles. x is [slice][d=256][n=1024].
// XT[slice][n][chunk^(n&7)] bf16 (16B-chunk XOR swizzle, conflict-free Kmd
// ds_reads).  XV[slice][cc=m>>3][d][j=m&7] bf16 (16B cells, V B-frags contig).
__global__ __launch_bounds__(256) void prep_kernel(const float* __restrict__ x,
                                                   unsigned short* __restrict__ XT,
                                                   unsigned short* __restrict__ XV) {
    __shared__ __align__(16) unsigned char smem[16384];
    int bid = blockIdx.x;
    int t = threadIdx.x;
    if (bid < 640) {
        uint4* T = (uint4*)smem;                      // [32cc][32d'] 16KB
        int slice = bid >> 5, w = bid & 31;
        int cc0 = (w & 3) * 32, d0 = (w >> 2) * 32;
        const float* xs = x + slice * 262144;
        int ccl = t & 31, dr = t >> 5;                // load: lanes->cc (1KB coalesced)
        #pragma unroll
        for (int p = 0; p < 4; ++p) {
            int dl = p * 8 + dr;
            const float* src = xs + (d0 + dl) * 1024 + (cc0 + ccl) * 8;
            float4 a = *(const float4*)(src);
            float4 b = *(const float4*)(src + 4);
            uint4 o;
            o.x = pack_bf16_rne(a.x, a.y); o.y = pack_bf16_rne(a.z, a.w);
            o.z = pack_bf16_rne(b.x, b.y); o.w = pack_bf16_rne(b.z, b.w);
            T[ccl * 32 + (dl ^ ccl)] = o;             // XOR-swizzled cell
        }
        __syncthreads();
        unsigned short* xv = XV + slice * 262144;
        int dl2 = t & 31, cr = t >> 5;                // store: lanes->d (512B segments)
        #pragma unroll
        for (int p = 0; p < 4; ++p) {
            int ccl2 = p * 8 + cr;
            uint4 o = T[ccl2 * 32 + (dl2 ^ ccl2)];
            *(uint4*)(xv + ((cc0 + ccl2) * 256 + d0 + dl2) * 8) = o;
        }
    } else {
        unsigned long long* TX = (unsigned long long*)smem;   // [64n][32dq] 8B, 16KB
        int b = bid - 640;
        int slice = b >> 5, w = b & 31;
        int d0 = (w & 1) * 128, n0 = (w >> 1) * 64;
        const float* xs = x + slice * 262144;
        int nq = t & 15, dqh = t >> 4;
        #pragma unroll
        for (int p = 0; p < 2; ++p) {
            int dq = p * 16 + dqh;                    // d = d0 + dq*4
            const float* src = xs + (d0 + dq * 4) * 1024 + n0 + nq * 4;
            float4 r0 = *(const float4*)(src);
            float4 r1 = *(const float4*)(src + 1024);
            float4 r2 = *(const float4*)(src + 2048);
            float4 r3 = *(const float4*)(src + 3072);
            const float* f0 = (const float*)&r0; const float* f1 = (const float*)&r1;
            const float* f2 = (const float*)&r2; const float* f3 = (const float*)&r3;
            #pragma unroll
            for (int j = 0; j < 4; ++j) {
                int nl2 = nq * 4 + j;
                unsigned long long q = (unsigned long long)pack_bf16_rne(f0[j], f1[j])
                    | ((unsigned long long)pack_bf16_rne(f2[j], f3[j]) << 32);
                TX[nl2 * 32 + (dq ^ (nl2 & 31))] = q;
            }
        }
        __syncthreads();
        unsigned short* xt = XT + slice * 262144;
        int ch = t & 15, nr = t >> 4;
        #pragma unroll
        for (int p = 0; p < 4; ++p) {
            int nl2 = p * 16 + nr;
            unsigned long long qlo = TX[nl2 * 32 + ((ch * 2) ^ (nl2 & 31))];
            unsigned long long qhi = TX[nl2 * 32 + ((ch * 2 + 1) ^ (nl2 & 31))];
            uint4 o = make_uint4((unsigned int)qlo, (unsigned int)(qlo >> 32),
                                 (unsigned int)qhi, (unsigned int)(qhi >> 32));
            *(uint4*)(xt + (n0 + nl2) * 256 + ((((d0 >> 3) + ch) ^ (nl2 & 7)) * 8)) = o;
        }
    }
}

__global__ __launch_bounds__(256, 2) void attn_kernel(const unsigned short* __restrict__ XT,
                                                      const unsigned short* __restrict__ XV,
                                                      const int* __restrict__ beta,
                                                      float* __restrict__ out) {
    __shared__ __align__(16) unsigned short Kmd[2][64 * 256]; // 2x32KB K-tile dbuf
    __shared__ __align__(16) unsigned short Pb[2][32 * 64];   // P dbuf, 8KB
    __shared__ float Lpart[4 * 32];
    __shared__ __align__(16) float Ltot[32];

    int bid = blockIdx.x;
    int t = ((bid & 7) * 80) + (bid >> 3);      // XCD-locality swizzle (640 blocks)
    int slice = t >> 5, qh = t & 31;

    int tid = threadIdx.x;
    int lane = tid & 63, wv = tid >> 6;
    int nl = lane & 15, g = lane >> 4;          // 16x16 frame
    int lo = lane & 31, hi = lane >> 5;         // 32x32 frame

    const unsigned short* xt_s = XT + slice * 262144;
    const unsigned short* xv_s = XV + slice * 262144;
    float cscale = (float)(beta[0]) * 1.44269504089f;   // beta * log2(e)

    // kdma(kt)->buf: each wave stages ONLY its own 8 chunks (rows wv*16..+16)
    // and reads only those rows -> K staging is wave-private, needs no barrier.
    auto kdma = [&](int kt, int buf) {
        const unsigned short* gk = xt_s + kt * 16384;
        #pragma unroll
        for (int i = 0; i < 8; ++i) {
            int ch = wv * 8 + i;
            GLD16(gk + ch * 512 + lane * 8, &Kmd[buf][ch * 512]);
        }
    };

    // ---- prologue: KDMA(0)->b0, KDMA(1)->b1 FIRST (oldest in vm queue) ----
    kdma(0, 0);
    kdma(1, 1);
    MEMFENCE();

    // ---- Q fragments (2 strips of 16 n) + fixed softmax max per column ----
    // (mcol consume waits the qf loads -> also drains KDMA(0/1): both ready
    //  at loop entry, so kt=0/1 top-waits are no-ops.)
    bf16x8 qf[2][8];
    float mcol[2];
    #pragma unroll
    for (int nq = 0; nq < 2; ++nq) {
        int n = qh * 32 + nq * 16 + nl;
        const unsigned short* qrow = xt_s + n * 256;
        float dg = 0.f;
        #pragma unroll
        for (int ks = 0; ks < 8; ++ks) {
            qf[nq][ks] = *(const bf16x8*)(qrow + (((ks * 4 + g) ^ (n & 7)) * 8));
            const unsigned int* qu = (const unsigned int*)&qf[nq][ks];
            #pragma unroll
            for (int w = 0; w < 4; ++w) {
                float flo = __uint_as_float(qu[w] << 16);
                float fhi = __uint_as_float(qu[w] & 0xFFFF0000u);
                dg = fmaf(flo, flo, dg);
                dg = fmaf(fhi, fhi, dg);
            }
        }
        dg += __shfl_xor(dg, 16);
        dg += __shfl_xor(dg, 32);
        mcol[nq] = dg * cscale;
    }

    f32x16 acc[2];                   // O[32n x 64d]: wave owns d in [wv*64,+64)
    acc[0] = (f32x16)(0.f); acc[1] = (f32x16)(0.f);
    float lac0 = 0.f, lac1 = 0.f;

    // vf(kt,ks,db) = XV cell (cc = kt*8 + ks*2 + hi, d = wv*64 + db*32 + lo)
    const unsigned short* vb = xv_s + (hi * 256 + wv * 64 + lo) * 8;
    bf16x8 vf[8];
    MEMFENCE();
    #pragma unroll
    for (int ks = 0; ks < 4; ++ks) {
        vf[ks * 2]     = *(const bf16x8*)(vb + ks * 4096);
        vf[ks * 2 + 1] = *(const bf16x8*)(vb + ks * 4096 + 256);
    }
    // vm queue at loop top (kt=0): [vf(0) x8] (KDMA 0/1 drained in prologue)

    for (int kt = 0; kt < 16; ++kt) {
        // ---- top wait: KDMA(kt) landed in Kmd[kt&1]. Steady state queue:
        // [KDMA(kt) x8 oldest, KDMA(kt+1) x8, vf(kt) x8] -> vmcnt(16).
        // kt=15: KDMA(16/17) never issued -> only vf(15) newer -> vmcnt(8).
        if (kt < 15) {
            __asm__ volatile("s_waitcnt vmcnt(16)" ::: "memory");
        } else {
            __asm__ volatile("s_waitcnt vmcnt(8)" ::: "memory");
        }
        __builtin_amdgcn_sched_barrier(0);

        const unsigned short* kmd_row = &Kmd[kt & 1][(wv * 16 + nl) * 256];

        // ---- S(kt): wave's own 16m rows x both 16n strips (A-frag reused) ----
        f32x4 s0 = {0.f,0.f,0.f,0.f}, s1 = {0.f,0.f,0.f,0.f};
        #pragma unroll
        for (int ks = 0; ks < 8; ++ks) {
            bf16x8 af = *(const bf16x8*)(kmd_row + (((ks * 4 + g) ^ (nl & 7)) * 8));
            s0 = __builtin_amdgcn_mfma_f32_16x16x32_bf16(af, qf[0][ks], s0, 0, 0, 0);
            s1 = __builtin_amdgcn_mfma_f32_16x16x32_bf16(af, qf[1][ks], s1, 0, 0, 0);
        }

        // ---- softmax (fixed max) + P write -> Pb[kt&1] ----
        {
            float p0 = exp2f(fmaf(s0[0], cscale, -mcol[0]));
            float p1 = exp2f(fmaf(s0[1], cscale, -mcol[0]));
            float p2 = exp2f(fmaf(s0[2], cscale, -mcol[0]));
            float p3 = exp2f(fmaf(s0[3], cscale, -mcol[0]));
            lac0 += (p0 + p1) + (p2 + p3);
            *(uint2*)(&Pb[kt & 1][nl * 64 + (((wv * 2 + (g >> 1)) ^ (nl & 7)) * 8) + (g & 1) * 4]) =
                make_uint2(pack2_trunc(p0, p1), pack2_trunc(p2, p3));
        }
        {
            float p0 = exp2f(fmaf(s1[0], cscale, -mcol[1]));
            float p1 = exp2f(fmaf(s1[1], cscale, -mcol[1]));
            float p2 = exp2f(fmaf(s1[2], cscale, -mcol[1]));
            float p3 = exp2f(fmaf(s1[3], cscale, -mcol[1]));
            lac1 += (p0 + p1) + (p2 + p3);
            *(uint2*)(&Pb[kt & 1][(16 + nl) * 64 + (((wv * 2 + (g >> 1)) ^ (nl & 7)) * 8) + (g & 1) * 4]) =
                make_uint2(pack2_trunc(p0, p1), pack2_trunc(p2, p3));
        }

        // restage Kmd[kt&1] for kt+2 (own af ds_reads retired: consumed by S
        // MFMAs above). ~1.4 iterations of DMA flight before its top-wait.
        if (kt < 14) kdma(kt + 2, kt & 1);
        MEMFENCE();

        LDS_BARRIER();               // the ONLY barrier per kt: P(kt) visible

        // ---- PV(kt): O += P[32n x 64m] * V[64m x 64d]; vf in regs.
        // vf(kt) is oldest in queue here -> compiler-counted wait leaves both
        // KDMA batches flying. Reload vf(kt+1) interleaved (1-iter flight).
        {
            const unsigned short* vnext = vb + (kt + 1) * 16384;
            #pragma unroll
            for (int ks = 0; ks < 4; ++ks) {
                bf16x8 pf = *(const bf16x8*)(&Pb[kt & 1][lo * 64 + (((ks * 2 + hi) ^ (lo & 7)) * 8)]);
                acc[0] = __builtin_amdgcn_mfma_f32_32x32x16_bf16(pf, vf[ks * 2],     acc[0], 0, 0, 0);
                acc[1] = __builtin_amdgcn_mfma_f32_32x32x16_bf16(pf, vf[ks * 2 + 1], acc[1], 0, 0, 0);
                if (kt < 15) {
                    vf[ks * 2]     = *(const bf16x8*)(vnext + ks * 4096);
                    vf[ks * 2 + 1] = *(const bf16x8*)(vnext + ks * 4096 + 256);
                }
            }
        }
    }

    // ---- epilogue: softmax denominators, scale, store ----
    lac0 += __shfl_xor(lac0, 16); lac0 += __shfl_xor(lac0, 32);
    lac1 += __shfl_xor(lac1, 16); lac1 += __shfl_xor(lac1, 32);
    if (lane < 16) {
        Lpart[wv * 32 + nl] = lac0;
        Lpart[wv * 32 + 16 + nl] = lac1;
    }
    LDS_BARRIER();
    if (tid < 32)
        Ltot[tid] = 1.f / (Lpart[tid] + Lpart[32 + tid] + Lpart[64 + tid] + Lpart[96 + tid]);
    LDS_BARRIER();

    float* outs = out + slice * 262144 + (qh * 32) * 256;
    #pragma unroll
    for (int rq = 0; rq < 4; ++rq) {
        f32x4 li = *(const f32x4*)(&Ltot[rq * 8 + hi * 4]);
        #pragma unroll
        for (int j = 0; j < 4; ++j) {
            int nloc = rq * 8 + hi * 4 + j;
            #pragma unroll
            for (int db = 0; db < 2; ++db)
                outs[nloc * 256 + wv * 64 + db * 32 + lo] = acc[db][rq * 4 + j] * li[j];
        }
    }
}

extern "C" void kernel_launch(void* const* d_in, const int* in_sizes, int n_in,
                              void* d_out, int out_size, void* d_ws, size_t ws_size,
                              hipStream_t stream) {
    const float* x = (const float*)d_in[0];
    const int* beta = (const int*)d_in[1];
    float* out = (float*)d_out;
    unsigned short* XT = (unsigned short*)d_ws;                 // 10,485,760 B
    unsigned short* XV = (unsigned short*)d_ws + 5242880;       // 10,485,760 B
    prep_kernel<<<1280, 256, 0, stream>>>(x, XT, XV);
    attn_kernel<<<640, 256, 0, stream>>>(XT, XV, beta, out);
}

// Round 6
// 118.207 us; speedup vs baseline: 1.2307x; 1.0087x over previous
//
#include <hip/hip_runtime.h>

// Attention, 20 slices of [N=1024, D=256]. R11: 64-row q-tiles, 320 blocks.
// Model (R5/R7/R10 fit): dur ~ per-CU L2->CU bytes. Each block streams the
// full 1MB slice regardless of q-rows -> doubling rows/block HALVES traffic
// per output. Kept identical to R7: wave-private K via LDS-DMA (m-group 16
// rows), V direct-to-reg from XV (wave = d-quarter), ONE lgkm-only barrier
// per kt, counted vmcnt(8) top-wait ([kdma(kt) x8 old, vf(kt) x8 new]).
// New: wave's S covers ALL 4 n-strips (strip0 Q in regs, strips 1-3 from a
// 24KB Qlds staged once); PV = 4x mfma_32x32x16 tiles -> acc 64 regs,
// O[64n x 64d] per wave. LDS 73.7KB -> 2 blocks/CU; 320 blocks all
// resident (no 512+128 tail). Reg peak ~185 of 256 cap (no spill margin).

typedef __attribute__((ext_vector_type(8))) short bf16x8;
typedef __attribute__((ext_vector_type(4))) float f32x4;
typedef __attribute__((ext_vector_type(16))) float f32x16;

#define GLD16(gp, lp) __builtin_amdgcn_global_load_lds( \
    (const __attribute__((address_space(1))) unsigned int*)(const void*)(gp), \
    (__attribute__((address_space(3))) unsigned int*)(void*)(lp), 16, 0, 0)

// LDS-only barrier: no vmcnt drain (K-DMA + vf global loads stay in flight)
#define LDS_BARRIER() __asm__ volatile("s_waitcnt lgkmcnt(0)\ns_barrier" ::: "memory")
#define MEMFENCE()    __asm__ volatile("" ::: "memory")
// wait the 8 oldest VMEM ops (this wave's K-DMA); 8 newer vf loads keep flying
#define WAIT_KDMA()   do { __asm__ volatile("s_waitcnt vmcnt(8)" ::: "memory"); \
                           __builtin_amdgcn_sched_barrier(0); } while (0)

__device__ __forceinline__ unsigned int pack_bf16_rne(float a, float b) {
    unsigned int ua = __float_as_uint(a); ua += 0x7FFFu + ((ua >> 16) & 1u);
    unsigned int ub = __float_as_uint(b); ub += 0x7FFFu + ((ub >> 16) & 1u);
    return (ua >> 16) | (ub & 0xFFFF0000u);
}
__device__ __forceinline__ unsigned int pack2_trunc(float lo, float hi) {
    return __builtin_amdgcn_perm(__float_as_uint(hi), __float_as_uint(lo), 0x07060302u);
}

// Fused prep (unchanged): bid<640 -> XV tiles, else -> XT tiles.
// XT[slice][n][chunk^(n&7)] bf16.  XV[slice][cc=m>>3][d][j=m&7] bf16.
__global__ __launch_bounds__(256) void prep_kernel(const float* __restrict__ x,
                                                   unsigned short* __restrict__ XT,
                                                   unsigned short* __restrict__ XV) {
    __shared__ __align__(16) unsigned char smem[16384];
    int bid = blockIdx.x;
    int t = threadIdx.x;
    if (bid < 640) {
        uint4* T = (uint4*)smem;                      // [32cc][32d'] 16KB
        int slice = bid >> 5, w = bid & 31;
        int cc0 = (w & 3) * 32, d0 = (w >> 2) * 32;
        const float* xs = x + slice * 262144;
        int ccl = t & 31, dr = t >> 5;
        #pragma unroll
        for (int p = 0; p < 4; ++p) {
            int dl = p * 8 + dr;
            const float* src = xs + (d0 + dl) * 1024 + (cc0 + ccl) * 8;
            float4 a = *(const float4*)(src);
            float4 b = *(const float4*)(src + 4);
            uint4 o;
            o.x = pack_bf16_rne(a.x, a.y); o.y = pack_bf16_rne(a.z, a.w);
            o.z = pack_bf16_rne(b.x, b.y); o.w = pack_bf16_rne(b.z, b.w);
            T[ccl * 32 + (dl ^ ccl)] = o;
        }
        __syncthreads();
        unsigned short* xv = XV + slice * 262144;
        int dl2 = t & 31, cr = t >> 5;
        #pragma unroll
        for (int p = 0; p < 4; ++p) {
            int ccl2 = p * 8 + cr;
            uint4 o = T[ccl2 * 32 + (dl2 ^ ccl2)];
            *(uint4*)(xv + ((cc0 + ccl2) * 256 + d0 + dl2) * 8) = o;
        }
    } else {
        unsigned long long* TX = (unsigned long long*)smem;   // [64n][32dq] 16KB
        int b = bid - 640;
        int slice = b >> 5, w = b & 31;
        int d0 = (w & 1) * 128, n0 = (w >> 1) * 64;
        const float* xs = x + slice * 262144;
        int nq = t & 15, dqh = t >> 4;
        #pragma unroll
        for (int p = 0; p < 2; ++p) {
            int dq = p * 16 + dqh;
            const float* src = xs + (d0 + dq * 4) * 1024 + n0 + nq * 4;
            float4 r0 = *(const float4*)(src);
            float4 r1 = *(const float4*)(src + 1024);
            float4 r2 = *(const float4*)(src + 2048);
            float4 r3 = *(const float4*)(src + 3072);
            const float* f0 = (const float*)&r0; const float* f1 = (const float*)&r1;
            const float* f2 = (const float*)&r2; const float* f3 = (const float*)&r3;
            #pragma unroll
            for (int j = 0; j < 4; ++j) {
                int nl2 = nq * 4 + j;
                unsigned long long q = (unsigned long long)pack_bf16_rne(f0[j], f1[j])
                    | ((unsigned long long)pack_bf16_rne(f2[j], f3[j]) << 32);
                TX[nl2 * 32 + (dq ^ (nl2 & 31))] = q;
            }
        }
        __syncthreads();
        unsigned short* xt = XT + slice * 262144;
        int ch = t & 15, nr = t >> 4;
        #pragma unroll
        for (int p = 0; p < 4; ++p) {
            int nl2 = p * 16 + nr;
            unsigned long long qlo = TX[nl2 * 32 + ((ch * 2) ^ (nl2 & 31))];
            unsigned long long qhi = TX[nl2 * 32 + ((ch * 2 + 1) ^ (nl2 & 31))];
            uint4 o = make_uint4((unsigned int)qlo, (unsigned int)(qlo >> 32),
                                 (unsigned int)qhi, (unsigned int)(qhi >> 32));
            *(uint4*)(xt + (n0 + nl2) * 256 + ((((d0 >> 3) + ch) ^ (nl2 & 7)) * 8)) = o;
        }
    }
}

__global__ __launch_bounds__(256, 2) void attn_kernel(const unsigned short* __restrict__ XT,
                                                      const unsigned short* __restrict__ XV,
                                                      const int* __restrict__ beta,
                                                      float* __restrict__ out) {
    __shared__ __align__(16) unsigned short Kmd[64 * 256];    // 32KB K-tile, wave-private rows
    __shared__ __align__(16) unsigned short Qlds[48 * 256];   // 24KB Q rows +16..+64 (static)
    __shared__ __align__(16) unsigned short Pb[2][64 * 64];   // 16KB P dbuf [64n][64m]
    // epilogue scratch overlays Pb[0] (dead after last PV read of Pb[1])
    float* Lpart = (float*)&Pb[0][0];          // [4][64]
    float* Ltot  = (float*)&Pb[0][2048];       // [64]

    int bid = blockIdx.x;
    int t = ((bid & 7) * 40) + (bid >> 3);      // XCD swizzle (320 blocks)
    int slice = t >> 4, qh = t & 15;            // qh: 64-row q-tile index

    int tid = threadIdx.x;
    int lane = tid & 63, wv = tid >> 6;
    int nl = lane & 15, g = lane >> 4;          // 16x16 frame
    int lo = lane & 31, hi = lane >> 5;         // 32x32 frame

    const unsigned short* xt_s = XT + slice * 262144;
    const unsigned short* xv_s = XV + slice * 262144;
    float cscale = (float)(beta[0]) * 1.44269504089f;   // beta * log2(e)

    auto kdma = [&](int kt) {                   // wave-private: own 8 chunks = own 16 m-rows
        const unsigned short* gk = xt_s + kt * 16384;
        #pragma unroll
        for (int i = 0; i < 8; ++i) {
            int ch = wv * 8 + i;
            GLD16(gk + ch * 512 + lane * 8, &Kmd[ch * 512]);
        }
    };

    // ---- prologue: K-DMA(0), then Q-stage (rows +16..+64 -> Qlds) ----
    kdma(0);
    {
        const unsigned short* gq = xt_s + (qh * 64 + 16) * 256;
        #pragma unroll
        for (int i = 0; i < 6; ++i) {
            int ch = wv * 6 + i;
            GLD16(gq + ch * 512 + lane * 8, &Qlds[ch * 512]);
        }
    }
    MEMFENCE();

    // ---- strip0 Q fragments (regs) + mcol[0] ----
    bf16x8 qf[8];
    float mcol[4];
    {
        int n = qh * 64 + nl;
        const unsigned short* qrow = xt_s + n * 256;
        float dg = 0.f;
        #pragma unroll
        for (int ks = 0; ks < 8; ++ks) {
            qf[ks] = *(const bf16x8*)(qrow + (((ks * 4 + g) ^ (n & 7)) * 8));
            const unsigned int* qu = (const unsigned int*)&qf[ks];
            #pragma unroll
            for (int w = 0; w < 4; ++w) {
                float flo = __uint_as_float(qu[w] << 16);
                float fhi = __uint_as_float(qu[w] & 0xFFFF0000u);
                dg = fmaf(flo, flo, dg);
                dg = fmaf(fhi, fhi, dg);
            }
        }
        dg += __shfl_xor(dg, 16);
        dg += __shfl_xor(dg, 32);
        mcol[0] = dg * cscale;
    }

    // vf(0): d-quarter = wv, cells (cc = ks*2+hi, d = wv*64 + dt*32 + lo)
    const unsigned short* vb = xv_s + (hi * 256 + wv * 64 + lo) * 8;
    bf16x8 vf[8];
    MEMFENCE();
    #pragma unroll
    for (int ks = 0; ks < 4; ++ks) {
        vf[ks * 2]     = *(const bf16x8*)(vb + ks * 4096);
        vf[ks * 2 + 1] = *(const bf16x8*)(vb + ks * 4096 + 256);
    }
    // queue: [kdma(0) 8, Qstage 6, qf0 8, vf(0) 8]; wait all but vf(0):
    __asm__ volatile("s_waitcnt vmcnt(8)" ::: "memory");
    __builtin_amdgcn_sched_barrier(0);
    LDS_BARRIER();                              // Qlds + Kmd(0) visible block-wide

    // ---- mcol[1..3] from Qlds ----
    #pragma unroll
    for (int st = 1; st < 4; ++st) {
        const unsigned short* qrow = &Qlds[((st - 1) * 16 + nl) * 256];
        float dg = 0.f;
        #pragma unroll
        for (int ks = 0; ks < 8; ++ks) {
            bf16x8 qv = *(const bf16x8*)(qrow + (((ks * 4 + g) ^ (nl & 7)) * 8));
            const unsigned int* qu = (const unsigned int*)&qv;
            #pragma unroll
            for (int w = 0; w < 4; ++w) {
                float flo = __uint_as_float(qu[w] << 16);
                float fhi = __uint_as_float(qu[w] & 0xFFFF0000u);
                dg = fmaf(flo, flo, dg);
                dg = fmaf(fhi, fhi, dg);
            }
        }
        dg += __shfl_xor(dg, 16);
        dg += __shfl_xor(dg, 32);
        mcol[st] = dg * cscale;
    }

    f32x16 acc[2][2];                 // O[nb*32+.. n][wv*64 + dt*32 + lo]
    acc[0][0] = (f32x16)(0.f); acc[0][1] = (f32x16)(0.f);
    acc[1][0] = (f32x16)(0.f); acc[1][1] = (f32x16)(0.f);
    float lac[4] = {0.f, 0.f, 0.f, 0.f};

    const unsigned short* kmd_row = &Kmd[(wv * 16 + nl) * 256];
    const unsigned short* q1 = &Qlds[nl * 256];
    const unsigned short* q2 = &Qlds[(16 + nl) * 256];
    const unsigned short* q3 = &Qlds[(32 + nl) * 256];

    for (int kt = 0; kt < 16; ++kt) {
        WAIT_KDMA();                 // vmcnt(8): Kmd(kt) landed; vf(kt) flying

        // ---- S(kt): own 16m x all 64n (af reused across 4 strips) ----
        f32x4 s0 = {0.f,0.f,0.f,0.f}, s1 = {0.f,0.f,0.f,0.f};
        f32x4 s2 = {0.f,0.f,0.f,0.f}, s3 = {0.f,0.f,0.f,0.f};
        #pragma unroll
        for (int ks = 0; ks < 8; ++ks) {
            int ch = ((ks * 4 + g) ^ (nl & 7)) * 8;
            bf16x8 af = *(const bf16x8*)(kmd_row + ch);
            s0 = __builtin_amdgcn_mfma_f32_16x16x32_bf16(af, qf[ks], s0, 0, 0, 0);
            s1 = __builtin_amdgcn_mfma_f32_16x16x32_bf16(af, *(const bf16x8*)(q1 + ch), s1, 0, 0, 0);
            s2 = __builtin_amdgcn_mfma_f32_16x16x32_bf16(af, *(const bf16x8*)(q2 + ch), s2, 0, 0, 0);
            s3 = __builtin_amdgcn_mfma_f32_16x16x32_bf16(af, *(const bf16x8*)(q3 + ch), s3, 0, 0, 0);
        }

        // ---- softmax (fixed max) + P write, 4 strips -> Pb[kt&1] ----
        {
            f32x4 sv[4] = {s0, s1, s2, s3};
            #pragma unroll
            for (int st = 0; st < 4; ++st) {
                float p0 = exp2f(fmaf(sv[st][0], cscale, -mcol[st]));
                float p1 = exp2f(fmaf(sv[st][1], cscale, -mcol[st]));
                float p2 = exp2f(fmaf(sv[st][2], cscale, -mcol[st]));
                float p3 = exp2f(fmaf(sv[st][3], cscale, -mcol[st]));
                lac[st] += (p0 + p1) + (p2 + p3);
                *(uint2*)(&Pb[kt & 1][(st * 16 + nl) * 64 +
                                      (((wv * 2 + (g >> 1)) ^ (nl & 7)) * 8) + (g & 1) * 4]) =
                    make_uint2(pack2_trunc(p0, p1), pack2_trunc(p2, p3));
            }
        }

        // restage own Kmd rows for kt+1 (af reads consumed by S MFMAs above)
        if (kt < 15) kdma(kt + 1);
        MEMFENCE();

        LDS_BARRIER();               // the ONLY barrier per kt: P(kt) visible

        // ---- PV(kt): O[64n x 64d] += P[64n x 64m] * V[64m x 64d] ----
        {
            const unsigned short* vnext = vb + (kt + 1) * 16384;
            #pragma unroll
            for (int ks = 0; ks < 4; ++ks) {
                int ch = ((ks * 2 + hi) ^ (lo & 7)) * 8;
                bf16x8 pf0 = *(const bf16x8*)(&Pb[kt & 1][lo * 64 + ch]);
                bf16x8 pf1 = *(const bf16x8*)(&Pb[kt & 1][(32 + lo) * 64 + ch]);
                acc[0][0] = __builtin_amdgcn_mfma_f32_32x32x16_bf16(pf0, vf[ks * 2],     acc[0][0], 0, 0, 0);
                acc[0][1] = __builtin_amdgcn_mfma_f32_32x32x16_bf16(pf0, vf[ks * 2 + 1], acc[0][1], 0, 0, 0);
                acc[1][0] = __builtin_amdgcn_mfma_f32_32x32x16_bf16(pf1, vf[ks * 2],     acc[1][0], 0, 0, 0);
                acc[1][1] = __builtin_amdgcn_mfma_f32_32x32x16_bf16(pf1, vf[ks * 2 + 1], acc[1][1], 0, 0, 0);
                if (kt < 15) {
                    vf[ks * 2]     = *(const bf16x8*)(vnext + ks * 4096);
                    vf[ks * 2 + 1] = *(const bf16x8*)(vnext + ks * 4096 + 256);
                }
            }
        }
        // queue at loop top: [kdma(kt+1) x8 oldest][vf(kt+1) x8] = 16
    }

    // ---- epilogue: denominators (overlays Pb[0]; PV(15) read only Pb[1]) ----
    #pragma unroll
    for (int st = 0; st < 4; ++st) {
        lac[st] += __shfl_xor(lac[st], 16);
        lac[st] += __shfl_xor(lac[st], 32);
    }
    if (lane < 16) {
        #pragma unroll
        for (int st = 0; st < 4; ++st) Lpart[wv * 64 + st * 16 + nl] = lac[st];
    }
    LDS_BARRIER();
    if (tid < 64)
        Ltot[tid] = 1.f / (Lpart[tid] + Lpart[64 + tid] + Lpart[128 + tid] + Lpart[192 + tid]);
    LDS_BARRIER();

    float* outs = out + slice * 262144 + (qh * 64) * 256;
    #pragma unroll
    for (int nb = 0; nb < 2; ++nb) {
        #pragma unroll
        for (int rq = 0; rq < 4; ++rq) {
            f32x4 li = *(const f32x4*)(&Ltot[nb * 32 + rq * 8 + hi * 4]);
            #pragma unroll
            for (int j = 0; j < 4; ++j) {
                int row = nb * 32 + rq * 8 + hi * 4 + j;
                #pragma unroll
                for (int dt = 0; dt < 2; ++dt)
                    outs[row * 256 + wv * 64 + dt * 32 + lo] = acc[nb][dt][rq * 4 + j] * li[j];
            }
        }
    }
}

extern "C" void kernel_launch(void* const* d_in, const int* in_sizes, int n_in,
                              void* d_out, int out_size, void* d_ws, size_t ws_size,
                              hipStream_t stream) {
    const float* x = (const float*)d_in[0];
    const int* beta = (const int*)d_in[1];
    float* out = (float*)d_out;
    unsigned short* XT = (unsigned short*)d_ws;                 // 10,485,760 B
    unsigned short* XV = (unsigned short*)d_ws + 5242880;       // 10,485,760 B
    prep_kernel<<<1280, 256, 0, stream>>>(x, XT, XV);
    attn_kernel<<<320, 256, 0, stream>>>(XT, XV, beta, out);
}

// Round 7
// 115.093 us; speedup vs baseline: 1.2640x; 1.0271x over previous
//
#include <hip/hip_runtime.h>

// Attention, 20 slices of [N=1024, D=256]. R12 = R7 with K moved LDS->regs.
// R7/R10/R11 triangulation: makespan = per-block serial time; LDS data path
// ~78% busy in BOTH R7 and R11 (ds_read 12cy/b128 + DMA writes + conflicts)
// while MFMA/VALU idle ~65%. Fix: delete Kmd entirely -- af fragments load
// global->VGPR from XT (R6 proved numerically; R6's 127us was purely the
// (256,3) 128-reg cap spill, 29MB/iter scratch). At (256,2) demand ~190 regs
// fits cap 256. LDS now holds ONLY double-buffered P (8KB): per-block-kt LDS
// traffic drops 84KB -> 20KB. No manual vmcnt: af/vf are register-destined,
// compiler scoreboard emits counted waits; af(kt+1) issued right after S(kt)
// (flight = softmax+barrier+PV), vf(kt+1) interleaved into PV(kt). One
// lgkm-only barrier per kt (P visibility), global loads fly across it.

typedef __attribute__((ext_vector_type(8))) short bf16x8;
typedef __attribute__((ext_vector_type(4))) float f32x4;
typedef __attribute__((ext_vector_type(16))) float f32x16;

// LDS-only barrier: no vmcnt drain (global loads stay in flight)
#define LDS_BARRIER() __asm__ volatile("s_waitcnt lgkmcnt(0)\ns_barrier" ::: "memory")

__device__ __forceinline__ unsigned int pack_bf16_rne(float a, float b) {
    unsigned int ua = __float_as_uint(a); ua += 0x7FFFu + ((ua >> 16) & 1u);
    unsigned int ub = __float_as_uint(b); ub += 0x7FFFu + ((ub >> 16) & 1u);
    return (ua >> 16) | (ub & 0xFFFF0000u);
}
__device__ __forceinline__ unsigned int pack2_trunc(float lo, float hi) {
    return __builtin_amdgcn_perm(__float_as_uint(hi), __float_as_uint(lo), 0x07060302u);
}

// Fused prep (unchanged from R7): bid<640 -> XV tiles, else -> XT tiles.
// XT[slice][n][chunk^(n&7)] bf16 (16B-chunk XOR swizzle; pure address math
// for the global af/qf gathers).  XV[slice][cc=m>>3][d][j=m&7] bf16.
__global__ __launch_bounds__(256) void prep_kernel(const float* __restrict__ x,
                                                   unsigned short* __restrict__ XT,
                                                   unsigned short* __restrict__ XV) {
    __shared__ __align__(16) unsigned char smem[16384];
    int bid = blockIdx.x;
    int t = threadIdx.x;
    if (bid < 640) {
        uint4* T = (uint4*)smem;                      // [32cc][32d'] 16KB
        int slice = bid >> 5, w = bid & 31;
        int cc0 = (w & 3) * 32, d0 = (w >> 2) * 32;
        const float* xs = x + slice * 262144;
        int ccl = t & 31, dr = t >> 5;
        #pragma unroll
        for (int p = 0; p < 4; ++p) {
            int dl = p * 8 + dr;
            const float* src = xs + (d0 + dl) * 1024 + (cc0 + ccl) * 8;
            float4 a = *(const float4*)(src);
            float4 b = *(const float4*)(src + 4);
            uint4 o;
            o.x = pack_bf16_rne(a.x, a.y); o.y = pack_bf16_rne(a.z, a.w);
            o.z = pack_bf16_rne(b.x, b.y); o.w = pack_bf16_rne(b.z, b.w);
            T[ccl * 32 + (dl ^ ccl)] = o;
        }
        __syncthreads();
        unsigned short* xv = XV + slice * 262144;
        int dl2 = t & 31, cr = t >> 5;
        #pragma unroll
        for (int p = 0; p < 4; ++p) {
            int ccl2 = p * 8 + cr;
            uint4 o = T[ccl2 * 32 + (dl2 ^ ccl2)];
            *(uint4*)(xv + ((cc0 + ccl2) * 256 + d0 + dl2) * 8) = o;
        }
    } else {
        unsigned long long* TX = (unsigned long long*)smem;   // [64n][32dq] 16KB
        int b = bid - 640;
        int slice = b >> 5, w = b & 31;
        int d0 = (w & 1) * 128, n0 = (w >> 1) * 64;
        const float* xs = x + slice * 262144;
        int nq = t & 15, dqh = t >> 4;
        #pragma unroll
        for (int p = 0; p < 2; ++p) {
            int dq = p * 16 + dqh;
            const float* src = xs + (d0 + dq * 4) * 1024 + n0 + nq * 4;
            float4 r0 = *(const float4*)(src);
            float4 r1 = *(const float4*)(src + 1024);
            float4 r2 = *(const float4*)(src + 2048);
            float4 r3 = *(const float4*)(src + 3072);
            const float* f0 = (const float*)&r0; const float* f1 = (const float*)&r1;
            const float* f2 = (const float*)&r2; const float* f3 = (const float*)&r3;
            #pragma unroll
            for (int j = 0; j < 4; ++j) {
                int nl2 = nq * 4 + j;
                unsigned long long q = (unsigned long long)pack_bf16_rne(f0[j], f1[j])
                    | ((unsigned long long)pack_bf16_rne(f2[j], f3[j]) << 32);
                TX[nl2 * 32 + (dq ^ (nl2 & 31))] = q;
            }
        }
        __syncthreads();
        unsigned short* xt = XT + slice * 262144;
        int ch = t & 15, nr = t >> 4;
        #pragma unroll
        for (int p = 0; p < 4; ++p) {
            int nl2 = p * 16 + nr;
            unsigned long long qlo = TX[nl2 * 32 + ((ch * 2) ^ (nl2 & 31))];
            unsigned long long qhi = TX[nl2 * 32 + ((ch * 2 + 1) ^ (nl2 & 31))];
            uint4 o = make_uint4((unsigned int)qlo, (unsigned int)(qlo >> 32),
                                 (unsigned int)qhi, (unsigned int)(qhi >> 32));
            *(uint4*)(xt + (n0 + nl2) * 256 + ((((d0 >> 3) + ch) ^ (nl2 & 7)) * 8)) = o;
        }
    }
}

__global__ __launch_bounds__(256, 2) void attn_kernel(const unsigned short* __restrict__ XT,
                                                      const unsigned short* __restrict__ XV,
                                                      const int* __restrict__ beta,
                                                      float* __restrict__ out) {
    __shared__ __align__(16) unsigned short Pb[2][32 * 64];   // P dbuf, 8KB: ONLY LDS
    __shared__ float Lpart[4 * 32];
    __shared__ __align__(16) float Ltot[32];

    int bid = blockIdx.x;
    int t = ((bid & 7) * 80) + (bid >> 3);      // XCD-locality swizzle (640 blocks)
    int slice = t >> 5, qh = t & 31;

    int tid = threadIdx.x;
    int lane = tid & 63, wv = tid >> 6;
    int nl = lane & 15, g = lane >> 4;          // 16x16 frame
    int lo = lane & 31, hi = lane >> 5;         // 32x32 frame

    const unsigned short* xt_s = XT + slice * 262144;
    const unsigned short* xv_s = XV + slice * 262144;
    float cscale = (float)(beta[0]) * 1.44269504089f;   // beta * log2(e)

    // K-fragment base: row (wv*16+nl), chunk XOR uses nl&7 (kt*64, wv*16 are
    // multiples of 8). Per-lane fixed 16B offsets; kt advances by 16384.
    const unsigned short* kb = xt_s + (wv * 16 + nl) * 256;
    bf16x8 af[8];

    // ---- issue af(0) FIRST (longest flight: covers Q-norm prologue) ----
    #pragma unroll
    for (int ks = 0; ks < 8; ++ks)
        af[ks] = *(const bf16x8*)(kb + (((ks * 4 + g) ^ (nl & 7)) * 8));

    // ---- Q fragments (2 strips of 16 n) + fixed softmax max per column ----
    bf16x8 qf[2][8];
    float mcol[2];
    #pragma unroll
    for (int nq = 0; nq < 2; ++nq) {
        int n = qh * 32 + nq * 16 + nl;
        const unsigned short* qrow = xt_s + n * 256;
        float dg = 0.f;
        #pragma unroll
        for (int ks = 0; ks < 8; ++ks) {
            qf[nq][ks] = *(const bf16x8*)(qrow + (((ks * 4 + g) ^ (n & 7)) * 8));
            const unsigned int* qu = (const unsigned int*)&qf[nq][ks];
            #pragma unroll
            for (int w = 0; w < 4; ++w) {
                float flo = __uint_as_float(qu[w] << 16);
                float fhi = __uint_as_float(qu[w] & 0xFFFF0000u);
                dg = fmaf(flo, flo, dg);
                dg = fmaf(fhi, fhi, dg);
            }
        }
        dg += __shfl_xor(dg, 16);
        dg += __shfl_xor(dg, 32);
        mcol[nq] = dg * cscale;
    }

    f32x16 acc[2];                   // O[32n x 64d]: wave owns d in [wv*64,+64)
    acc[0] = (f32x16)(0.f); acc[1] = (f32x16)(0.f);
    float lac0 = 0.f, lac1 = 0.f;

    // vf(kt,ks,db) = XV cell (cc = kt*8 + ks*2 + hi, d = wv*64 + db*32 + lo)
    const unsigned short* vb = xv_s + (hi * 256 + wv * 64 + lo) * 8;
    bf16x8 vf[8];
    #pragma unroll
    for (int ks = 0; ks < 4; ++ks) {
        vf[ks * 2]     = *(const bf16x8*)(vb + ks * 4096);
        vf[ks * 2 + 1] = *(const bf16x8*)(vb + ks * 4096 + 256);
    }

    for (int kt = 0; kt < 16; ++kt) {
        // ---- S(kt): compiler scoreboard waits af regs (counted, minimal) ----
        f32x4 s0 = {0.f,0.f,0.f,0.f}, s1 = {0.f,0.f,0.f,0.f};
        #pragma unroll
        for (int ks = 0; ks < 8; ++ks) {
            s0 = __builtin_amdgcn_mfma_f32_16x16x32_bf16(af[ks], qf[0][ks], s0, 0, 0, 0);
            s1 = __builtin_amdgcn_mfma_f32_16x16x32_bf16(af[ks], qf[1][ks], s1, 0, 0, 0);
        }

        // ---- issue af(kt+1): flight = softmax + barrier + PV ----
        if (kt < 15) {
            const unsigned short* kkt = kb + (kt + 1) * 16384;
            #pragma unroll
            for (int ks = 0; ks < 8; ++ks)
                af[ks] = *(const bf16x8*)(kkt + (((ks * 4 + g) ^ (nl & 7)) * 8));
        }

        // ---- softmax (fixed max) + P write -> Pb[kt&1] ----
        {
            float p0 = exp2f(fmaf(s0[0], cscale, -mcol[0]));
            float p1 = exp2f(fmaf(s0[1], cscale, -mcol[0]));
            float p2 = exp2f(fmaf(s0[2], cscale, -mcol[0]));
            float p3 = exp2f(fmaf(s0[3], cscale, -mcol[0]));
            lac0 += (p0 + p1) + (p2 + p3);
            *(uint2*)(&Pb[kt & 1][nl * 64 + (((wv * 2 + (g >> 1)) ^ (nl & 7)) * 8) + (g & 1) * 4]) =
                make_uint2(pack2_trunc(p0, p1), pack2_trunc(p2, p3));
        }
        {
            float p0 = exp2f(fmaf(s1[0], cscale, -mcol[1]));
            float p1 = exp2f(fmaf(s1[1], cscale, -mcol[1]));
            float p2 = exp2f(fmaf(s1[2], cscale, -mcol[1]));
            float p3 = exp2f(fmaf(s1[3], cscale, -mcol[1]));
            lac1 += (p0 + p1) + (p2 + p3);
            *(uint2*)(&Pb[kt & 1][(16 + nl) * 64 + (((wv * 2 + (g >> 1)) ^ (nl & 7)) * 8) + (g & 1) * 4]) =
                make_uint2(pack2_trunc(p0, p1), pack2_trunc(p2, p3));
        }

        LDS_BARRIER();               // the ONLY barrier per kt: P(kt) visible

        // ---- PV(kt): O += P[32n x 64m] * V[64m x 64d]; vf regs; reload vf(kt+1)
        {
            const unsigned short* vnext = vb + (kt + 1) * 16384;
            #pragma unroll
            for (int ks = 0; ks < 4; ++ks) {
                bf16x8 pf = *(const bf16x8*)(&Pb[kt & 1][lo * 64 + (((ks * 2 + hi) ^ (lo & 7)) * 8)]);
                acc[0] = __builtin_amdgcn_mfma_f32_32x32x16_bf16(pf, vf[ks * 2],     acc[0], 0, 0, 0);
                acc[1] = __builtin_amdgcn_mfma_f32_32x32x16_bf16(pf, vf[ks * 2 + 1], acc[1], 0, 0, 0);
                if (kt < 15) {
                    vf[ks * 2]     = *(const bf16x8*)(vnext + ks * 4096);
                    vf[ks * 2 + 1] = *(const bf16x8*)(vnext + ks * 4096 + 256);
                }
            }
        }
    }

    // ---- epilogue: softmax denominators, scale, store ----
    lac0 += __shfl_xor(lac0, 16); lac0 += __shfl_xor(lac0, 32);
    lac1 += __shfl_xor(lac1, 16); lac1 += __shfl_xor(lac1, 32);
    if (lane < 16) {
        Lpart[wv * 32 + nl] = lac0;
        Lpart[wv * 32 + 16 + nl] = lac1;
    }
    LDS_BARRIER();
    if (tid < 32)
        Ltot[tid] = 1.f / (Lpart[tid] + Lpart[32 + tid] + Lpart[64 + tid] + Lpart[96 + tid]);
    LDS_BARRIER();

    float* outs = out + slice * 262144 + (qh * 32) * 256;
    #pragma unroll
    for (int rq = 0; rq < 4; ++rq) {
        f32x4 li = *(const f32x4*)(&Ltot[rq * 8 + hi * 4]);
        #pragma unroll
        for (int j = 0; j < 4; ++j) {
            int nloc = rq * 8 + hi * 4 + j;
            #pragma unroll
            for (int db = 0; db < 2; ++db)
                outs[nloc * 256 + wv * 64 + db * 32 + lo] = acc[db][rq * 4 + j] * li[j];
        }
    }
}

extern "C" void kernel_launch(void* const* d_in, const int* in_sizes, int n_in,
                              void* d_out, int out_size, void* d_ws, size_t ws_size,
                              hipStream_t stream) {
    const float* x = (const float*)d_in[0];
    const int* beta = (const int*)d_in[1];
    float* out = (float*)d_out;
    unsigned short* XT = (unsigned short*)d_ws;                 // 10,485,760 B
    unsigned short* XV = (unsigned short*)d_ws + 5242880;       // 10,485,760 B
    prep_kernel<<<1280, 256, 0, stream>>>(x, XT, XV);
    attn_kernel<<<640, 256, 0, stream>>>(XT, XV, beta, out);
}

// Round 8
// 114.420 us; speedup vs baseline: 1.2714x; 1.0059x over previous
//
#include <hip/hip_runtime.h>

// Attention, 20 slices of [N=1024, D=256]. R13 = R12 + merged kt-pairs:
// KVBLK 64->128, 8 barriers/block instead of 16. Elimination across R7-R12:
// DMA flight (R10), occupancy/tail (R8/R11), per-CU VMEM bytes (R11), LDS
// pipe (R12) all nulls -- every throughput resource ~75% idle. Survivor:
// per-kt serialization tax (barrier skew over 4 waves x 2 blocks + lgkm
// drain + exposed scoreboard waits + chain startup), ~constant per kt.
// This round halves the number of those events, holding all else fixed.
// P is quad-buffered (4x4KB, pair ping-pong): one barrier per merged iter
// is WAR-safe -- a pair is only rewritten after the barrier that followed
// every wave's PV reads of it. af/vf stay single-buffered (reg pressure
// unchanged ~190; R6/R8 spill lesson). S(kt1) af-wait ~100cy exposed by
// design -- traded against a full barrier event.

typedef __attribute__((ext_vector_type(8))) short bf16x8;
typedef __attribute__((ext_vector_type(4))) float f32x4;
typedef __attribute__((ext_vector_type(16))) float f32x16;

// LDS-only barrier: no vmcnt drain (global loads stay in flight)
#define LDS_BARRIER() __asm__ volatile("s_waitcnt lgkmcnt(0)\ns_barrier" ::: "memory")

__device__ __forceinline__ unsigned int pack_bf16_rne(float a, float b) {
    unsigned int ua = __float_as_uint(a); ua += 0x7FFFu + ((ua >> 16) & 1u);
    unsigned int ub = __float_as_uint(b); ub += 0x7FFFu + ((ub >> 16) & 1u);
    return (ua >> 16) | (ub & 0xFFFF0000u);
}
__device__ __forceinline__ unsigned int pack2_trunc(float lo, float hi) {
    return __builtin_amdgcn_perm(__float_as_uint(hi), __float_as_uint(lo), 0x07060302u);
}

// Fused prep (unchanged): bid<640 -> XV tiles, else -> XT tiles.
// XT[slice][n][chunk^(n&7)] bf16.  XV[slice][cc=m>>3][d][j=m&7] bf16.
__global__ __launch_bounds__(256) void prep_kernel(const float* __restrict__ x,
                                                   unsigned short* __restrict__ XT,
                                                   unsigned short* __restrict__ XV) {
    __shared__ __align__(16) unsigned char smem[16384];
    int bid = blockIdx.x;
    int t = threadIdx.x;
    if (bid < 640) {
        uint4* T = (uint4*)smem;                      // [32cc][32d'] 16KB
        int slice = bid >> 5, w = bid & 31;
        int cc0 = (w & 3) * 32, d0 = (w >> 2) * 32;
        const float* xs = x + slice * 262144;
        int ccl = t & 31, dr = t >> 5;
        #pragma unroll
        for (int p = 0; p < 4; ++p) {
            int dl = p * 8 + dr;
            const float* src = xs + (d0 + dl) * 1024 + (cc0 + ccl) * 8;
            float4 a = *(const float4*)(src);
            float4 b = *(const float4*)(src + 4);
            uint4 o;
            o.x = pack_bf16_rne(a.x, a.y); o.y = pack_bf16_rne(a.z, a.w);
            o.z = pack_bf16_rne(b.x, b.y); o.w = pack_bf16_rne(b.z, b.w);
            T[ccl * 32 + (dl ^ ccl)] = o;
        }
        __syncthreads();
        unsigned short* xv = XV + slice * 262144;
        int dl2 = t & 31, cr = t >> 5;
        #pragma unroll
        for (int p = 0; p < 4; ++p) {
            int ccl2 = p * 8 + cr;
            uint4 o = T[ccl2 * 32 + (dl2 ^ ccl2)];
            *(uint4*)(xv + ((cc0 + ccl2) * 256 + d0 + dl2) * 8) = o;
        }
    } else {
        unsigned long long* TX = (unsigned long long*)smem;   // [64n][32dq] 16KB
        int b = bid - 640;
        int slice = b >> 5, w = b & 31;
        int d0 = (w & 1) * 128, n0 = (w >> 1) * 64;
        const float* xs = x + slice * 262144;
        int nq = t & 15, dqh = t >> 4;
        #pragma unroll
        for (int p = 0; p < 2; ++p) {
            int dq = p * 16 + dqh;
            const float* src = xs + (d0 + dq * 4) * 1024 + n0 + nq * 4;
            float4 r0 = *(const float4*)(src);
            float4 r1 = *(const float4*)(src + 1024);
            float4 r2 = *(const float4*)(src + 2048);
            float4 r3 = *(const float4*)(src + 3072);
            const float* f0 = (const float*)&r0; const float* f1 = (const float*)&r1;
            const float* f2 = (const float*)&r2; const float* f3 = (const float*)&r3;
            #pragma unroll
            for (int j = 0; j < 4; ++j) {
                int nl2 = nq * 4 + j;
                unsigned long long q = (unsigned long long)pack_bf16_rne(f0[j], f1[j])
                    | ((unsigned long long)pack_bf16_rne(f2[j], f3[j]) << 32);
                TX[nl2 * 32 + (dq ^ (nl2 & 31))] = q;
            }
        }
        __syncthreads();
        unsigned short* xt = XT + slice * 262144;
        int ch = t & 15, nr = t >> 4;
        #pragma unroll
        for (int p = 0; p < 4; ++p) {
            int nl2 = p * 16 + nr;
            unsigned long long qlo = TX[nl2 * 32 + ((ch * 2) ^ (nl2 & 31))];
            unsigned long long qhi = TX[nl2 * 32 + ((ch * 2 + 1) ^ (nl2 & 31))];
            uint4 o = make_uint4((unsigned int)qlo, (unsigned int)(qlo >> 32),
                                 (unsigned int)qhi, (unsigned int)(qhi >> 32));
            *(uint4*)(xt + (n0 + nl2) * 256 + ((((d0 >> 3) + ch) ^ (nl2 & 7)) * 8)) = o;
        }
    }
}

__global__ __launch_bounds__(256, 2) void attn_kernel(const unsigned short* __restrict__ XT,
                                                      const unsigned short* __restrict__ XV,
                                                      const int* __restrict__ beta,
                                                      float* __restrict__ out) {
    __shared__ __align__(16) unsigned short Pb[4][32 * 64];   // P quad-buffer, 16KB
    __shared__ float Lpart[4 * 32];
    __shared__ __align__(16) float Ltot[32];

    int bid = blockIdx.x;
    int t = ((bid & 7) * 80) + (bid >> 3);      // XCD-locality swizzle (640 blocks)
    int slice = t >> 5, qh = t & 31;

    int tid = threadIdx.x;
    int lane = tid & 63, wv = tid >> 6;
    int nl = lane & 15, g = lane >> 4;          // 16x16 frame
    int lo = lane & 31, hi = lane >> 5;         // 32x32 frame

    const unsigned short* xt_s = XT + slice * 262144;
    const unsigned short* xv_s = XV + slice * 262144;
    float cscale = (float)(beta[0]) * 1.44269504089f;   // beta * log2(e)

    // K-fragment base: row (wv*16+nl); chunk XOR uses nl&7 (kt*64, wv*16 are
    // multiples of 8). kt advances by 16384 shorts.
    const unsigned short* kb = xt_s + (wv * 16 + nl) * 256;
    bf16x8 af[8];

    // ---- issue af(0) FIRST (longest flight: covers Q-norm prologue) ----
    #pragma unroll
    for (int ks = 0; ks < 8; ++ks)
        af[ks] = *(const bf16x8*)(kb + (((ks * 4 + g) ^ (nl & 7)) * 8));

    // ---- Q fragments (2 strips of 16 n) + fixed softmax max per column ----
    bf16x8 qf[2][8];
    float mcol[2];
    #pragma unroll
    for (int nq = 0; nq < 2; ++nq) {
        int n = qh * 32 + nq * 16 + nl;
        const unsigned short* qrow = xt_s + n * 256;
        float dg = 0.f;
        #pragma unroll
        for (int ks = 0; ks < 8; ++ks) {
            qf[nq][ks] = *(const bf16x8*)(qrow + (((ks * 4 + g) ^ (n & 7)) * 8));
            const unsigned int* qu = (const unsigned int*)&qf[nq][ks];
            #pragma unroll
            for (int w = 0; w < 4; ++w) {
                float flo = __uint_as_float(qu[w] << 16);
                float fhi = __uint_as_float(qu[w] & 0xFFFF0000u);
                dg = fmaf(flo, flo, dg);
                dg = fmaf(fhi, fhi, dg);
            }
        }
        dg += __shfl_xor(dg, 16);
        dg += __shfl_xor(dg, 32);
        mcol[nq] = dg * cscale;
    }

    f32x16 acc[2];                   // O[32n x 64d]: wave owns d in [wv*64,+64)
    acc[0] = (f32x16)(0.f); acc[1] = (f32x16)(0.f);
    float lac0 = 0.f, lac1 = 0.f;

    // vf(kt,ks,db) = XV cell (cc = kt*8 + ks*2 + hi, d = wv*64 + db*32 + lo)
    const unsigned short* vb = xv_s + (hi * 256 + wv * 64 + lo) * 8;
    bf16x8 vf[8];
    #pragma unroll
    for (int ks = 0; ks < 4; ++ks) {
        vf[ks * 2]     = *(const bf16x8*)(vb + ks * 4096);
        vf[ks * 2 + 1] = *(const bf16x8*)(vb + ks * 4096 + 256);
    }

    // S on current af into (sx, sy)
    auto S_mfma = [&](f32x4& sx, f32x4& sy) {
        #pragma unroll
        for (int ks = 0; ks < 8; ++ks) {
            sx = __builtin_amdgcn_mfma_f32_16x16x32_bf16(af[ks], qf[0][ks], sx, 0, 0, 0);
            sy = __builtin_amdgcn_mfma_f32_16x16x32_bf16(af[ks], qf[1][ks], sy, 0, 0, 0);
        }
    };
    auto issue_af = [&](int kt) {
        const unsigned short* kkt = kb + kt * 16384;
        #pragma unroll
        for (int ks = 0; ks < 8; ++ks)
            af[ks] = *(const bf16x8*)(kkt + (((ks * 4 + g) ^ (nl & 7)) * 8));
    };
    auto softmax_store = [&](const f32x4& s0, const f32x4& s1, int pbi) {
        {
            float p0 = exp2f(fmaf(s0[0], cscale, -mcol[0]));
            float p1 = exp2f(fmaf(s0[1], cscale, -mcol[0]));
            float p2 = exp2f(fmaf(s0[2], cscale, -mcol[0]));
            float p3 = exp2f(fmaf(s0[3], cscale, -mcol[0]));
            lac0 += (p0 + p1) + (p2 + p3);
            *(uint2*)(&Pb[pbi][nl * 64 + (((wv * 2 + (g >> 1)) ^ (nl & 7)) * 8) + (g & 1) * 4]) =
                make_uint2(pack2_trunc(p0, p1), pack2_trunc(p2, p3));
        }
        {
            float p0 = exp2f(fmaf(s1[0], cscale, -mcol[1]));
            float p1 = exp2f(fmaf(s1[1], cscale, -mcol[1]));
            float p2 = exp2f(fmaf(s1[2], cscale, -mcol[1]));
            float p3 = exp2f(fmaf(s1[3], cscale, -mcol[1]));
            lac1 += (p0 + p1) + (p2 + p3);
            *(uint2*)(&Pb[pbi][(16 + nl) * 64 + (((wv * 2 + (g >> 1)) ^ (nl & 7)) * 8) + (g & 1) * 4]) =
                make_uint2(pack2_trunc(p0, p1), pack2_trunc(p2, p3));
        }
    };
    auto PV = [&](int pbi, bool reload, int ktn) {
        const unsigned short* vnext = vb + ktn * 16384;
        #pragma unroll
        for (int ks = 0; ks < 4; ++ks) {
            bf16x8 pf = *(const bf16x8*)(&Pb[pbi][lo * 64 + (((ks * 2 + hi) ^ (lo & 7)) * 8)]);
            acc[0] = __builtin_amdgcn_mfma_f32_32x32x16_bf16(pf, vf[ks * 2],     acc[0], 0, 0, 0);
            acc[1] = __builtin_amdgcn_mfma_f32_32x32x16_bf16(pf, vf[ks * 2 + 1], acc[1], 0, 0, 0);
            if (reload) {
                vf[ks * 2]     = *(const bf16x8*)(vnext + ks * 4096);
                vf[ks * 2 + 1] = *(const bf16x8*)(vnext + ks * 4096 + 256);
            }
        }
    };

    for (int tt = 0; tt < 8; ++tt) {
        int kt0 = tt * 2;
        int pA = (tt & 1) * 2;       // pair ping-pong: {0,1} / {2,3}

        // ---- S(kt0) (af scoreboard wait; long flight from prev iter) ----
        f32x4 s0 = {0.f,0.f,0.f,0.f}, s1 = {0.f,0.f,0.f,0.f};
        S_mfma(s0, s1);
        issue_af(kt0 + 1);                    // flight: softmax(kt0)
        softmax_store(s0, s1, pA);

        // ---- S(kt1) (short af flight; traded for a removed barrier) ----
        f32x4 s2 = {0.f,0.f,0.f,0.f}, s3 = {0.f,0.f,0.f,0.f};
        S_mfma(s2, s3);
        if (tt < 7) issue_af(kt0 + 2);        // flight: sm(kt1)+barrier+2xPV
        softmax_store(s2, s3, pA + 1);

        LDS_BARRIER();               // ONE barrier per merged iter: PbA+PbB visible

        // ---- PV(kt0) then PV(kt1); vf reloads interleaved ----
        PV(pA, true, kt0 + 1);                // vf <- vf(kt1)
        PV(pA + 1, tt < 7, kt0 + 2);          // vf <- vf(next kt0)
    }

    // ---- epilogue: softmax denominators, scale, store ----
    lac0 += __shfl_xor(lac0, 16); lac0 += __shfl_xor(lac0, 32);
    lac1 += __shfl_xor(lac1, 16); lac1 += __shfl_xor(lac1, 32);
    if (lane < 16) {
        Lpart[wv * 32 + nl] = lac0;
        Lpart[wv * 32 + 16 + nl] = lac1;
    }
    LDS_BARRIER();
    if (tid < 32)
        Ltot[tid] = 1.f / (Lpart[tid] + Lpart[32 + tid] + Lpart[64 + tid] + Lpart[96 + tid]);
    LDS_BARRIER();

    float* outs = out + slice * 262144 + (qh * 32) * 256;
    #pragma unroll
    for (int rq = 0; rq < 4; ++rq) {
        f32x4 li = *(const f32x4*)(&Ltot[rq * 8 + hi * 4]);
        #pragma unroll
        for (int j = 0; j < 4; ++j) {
            int nloc = rq * 8 + hi * 4 + j;
            #pragma unroll
            for (int db = 0; db < 2; ++db)
                outs[nloc * 256 + wv * 64 + db * 32 + lo] = acc[db][rq * 4 + j] * li[j];
        }
    }
}

extern "C" void kernel_launch(void* const* d_in, const int* in_sizes, int n_in,
                              void* d_out, int out_size, void* d_ws, size_t ws_size,
                              hipStream_t stream) {
    const float* x = (const float*)d_in[0];
    const int* beta = (const int*)d_in[1];
    float* out = (float*)d_out;
    unsigned short* XT = (unsigned short*)d_ws;                 // 10,485,760 B
    unsigned short* XV = (unsigned short*)d_ws + 5242880;       // 10,485,760 B
    prep_kernel<<<1280, 256, 0, stream>>>(x, XT, XV);
    attn_kernel<<<640, 256, 0, stream>>>(XT, XV, beta, out);
}